// Round 1
// baseline (550.618 us; speedup 1.0000x reference)
//
#include <hip/hip_runtime.h>
#include <math.h>

#define N_NODE 20000
#define N_EDGE 200000
#define EMBED 256
#define PAIR 128
#define HEADS 16
#define HEAD_DIM 16
#define SCALING 0.25f
#define LNEPS 1e-5f

// ---------------- workspace layout (bytes) ----------------
// qkv   : N_NODE*768 f32             = 61,440,000
// ex    : N_EDGE*16 f32              = 12,800,000
// denom : N_NODE*16 f32              =  1,280,000
// vw    : N_NODE*48 f32              =  3,840,000
// mean  : N_NODE f32                 =     80,000
// rstd  : N_NODE f32                 =     80,000
#define WS_QKV   0
#define WS_EX    61440000
#define WS_DENOM 74240000
#define WS_VW    75520000
#define WS_MEAN  79360000
#define WS_RSTD  79440000

// ------------------------------------------------------------------
// Kernel 1: per-node LN stats (mean, rstd). One wave per node.
__global__ __launch_bounds__(256) void ln_stats_kernel(
    const float* __restrict__ query, float* __restrict__ mean_,
    float* __restrict__ rstd_) {
  int node = blockIdx.x * 4 + (threadIdx.x >> 6);
  int lane = threadIdx.x & 63;
  float4 a = *(const float4*)(query + (size_t)node * EMBED + lane * 4);
  float s  = a.x + a.y + a.z + a.w;
  float s2 = a.x*a.x + a.y*a.y + a.z*a.z + a.w*a.w;
  #pragma unroll
  for (int off = 32; off > 0; off >>= 1) {
    s  += __shfl_xor(s,  off);
    s2 += __shfl_xor(s2, off);
  }
  if (lane == 0) {
    float m = s * (1.0f / EMBED);
    float v = s2 * (1.0f / EMBED) - m * m;
    mean_[node] = m;
    rstd_[node] = rsqrtf(v + LNEPS);
  }
}

// ------------------------------------------------------------------
// Kernel 2: fused-LN GEMM.  C[n, j] (j in 0..767) = LN(query[n]) . Wsel[jl,:]
// 64x64 output tile, BK=16, 256 threads, 4x4 per-thread microtile.
#define BM 64
#define BN 64
#define BK 16
__global__ __launch_bounds__(256) void qkv_gemm_kernel(
    const float* __restrict__ query,
    const float* __restrict__ mean_, const float* __restrict__ rstd_,
    const float* __restrict__ ln_w, const float* __restrict__ ln_b,
    const float* __restrict__ Wq, const float* __restrict__ Wk,
    const float* __restrict__ Wv, float* __restrict__ qkv) {
  __shared__ float As[BK][BM];
  __shared__ float Bs[BK][BN];
  int tid = threadIdx.x;
  int tx = tid & 15, ty = tid >> 4;
  int row0 = blockIdx.x * BM;
  int col0 = blockIdx.y * BN;
  const float* W = (col0 < 256) ? Wq : (col0 < 512 ? Wk : Wv);
  int wrow0 = col0 & 255;

  int li = tid >> 2;          // 0..63: row within tile for loads
  int lk = (tid & 3) * 4;     // 0,4,8,12: k offset for loads

  float acc[4][4] = {};

  int an = row0 + li;
  float m = 0.0f, r = 0.0f;
  if (an < N_NODE) { m = mean_[an]; r = rstd_[an]; }

  for (int k0 = 0; k0 < EMBED; k0 += BK) {
    // stage A (LN applied on the fly), transposed: As[k][n]
    {
      float4 a = make_float4(0.f, 0.f, 0.f, 0.f);
      if (an < N_NODE)
        a = *(const float4*)(query + (size_t)an * EMBED + k0 + lk);
      float4 w4 = *(const float4*)(ln_w + k0 + lk);
      float4 b4 = *(const float4*)(ln_b + k0 + lk);
      As[lk + 0][li] = (a.x - m) * r * w4.x + b4.x;
      As[lk + 1][li] = (a.y - m) * r * w4.y + b4.y;
      As[lk + 2][li] = (a.z - m) * r * w4.z + b4.z;
      As[lk + 3][li] = (a.w - m) * r * w4.w + b4.w;
    }
    // stage B: Bs[k][j] = W[wrow0+j][k0+k]
    {
      float4 b = *(const float4*)(W + (size_t)(wrow0 + li) * EMBED + k0 + lk);
      Bs[lk + 0][li] = b.x;
      Bs[lk + 1][li] = b.y;
      Bs[lk + 2][li] = b.z;
      Bs[lk + 3][li] = b.w;
    }
    __syncthreads();
    #pragma unroll
    for (int kk = 0; kk < BK; kk++) {
      float4 a4 = *(const float4*)&As[kk][ty * 4];
      float4 b4 = *(const float4*)&Bs[kk][tx * 4];
      float av[4] = {a4.x, a4.y, a4.z, a4.w};
      float bv[4] = {b4.x, b4.y, b4.z, b4.w};
      #pragma unroll
      for (int i = 0; i < 4; i++)
        #pragma unroll
        for (int j = 0; j < 4; j++)
          acc[i][j] += av[i] * bv[j];
    }
    __syncthreads();
  }
  #pragma unroll
  for (int i = 0; i < 4; i++) {
    int n = row0 + ty * 4 + i;
    if (n < N_NODE) {
      float4 o = make_float4(acc[i][0], acc[i][1], acc[i][2], acc[i][3]);
      *(float4*)(qkv + (size_t)n * 768 + col0 + tx * 4) = o;
    }
  }
}

// ------------------------------------------------------------------
// Kernel 3: vw[n, h, c] = sum_d v[n, h*16+d] * Wf_c[h*16+d]
__global__ __launch_bounds__(256) void vw_kernel(
    const float* __restrict__ qkv,
    const float* __restrict__ Wf1, const float* __restrict__ Wf2,
    const float* __restrict__ Wf3, float* __restrict__ vw) {
  int idx = blockIdx.x * blockDim.x + threadIdx.x;
  if (idx >= N_NODE * 48) return;
  int n = idx / 48;
  int rr = idx - n * 48;
  int h = rr / 3, c = rr - h * 3;
  const float* Wf = (c == 0) ? Wf1 : (c == 1 ? Wf2 : Wf3);
  const float* v = qkv + (size_t)n * 768 + 512 + h * 16;
  const float* w = Wf + h * 16;
  float s = 0.f;
  #pragma unroll
  for (int d = 0; d < 16; d++) s += v[d] * w[d];
  vw[idx] = s;
}

// ------------------------------------------------------------------
// Kernel 4: init denom=0, out = bias
__global__ __launch_bounds__(256) void init_kernel(
    float* __restrict__ denom, float* __restrict__ out,
    const float* __restrict__ bf1, const float* __restrict__ bf2,
    const float* __restrict__ bf3) {
  int i = blockIdx.x * blockDim.x + threadIdx.x;
  if (i < N_NODE * HEADS) denom[i] = 0.0f;
  if (i < N_NODE) {
    out[i * 3 + 0] = bf1[0];
    out[i * 3 + 1] = bf2[0];
    out[i * 3 + 2] = bf3[0];
  }
}

// ------------------------------------------------------------------
// Kernel 5: per-edge logits -> ex, denom.  One wave per edge, 4 waves/block.
__global__ __launch_bounds__(256) void edge_logits_kernel(
    const int* __restrict__ edge_index, const float* __restrict__ pair,
    const float* __restrict__ pln_w, const float* __restrict__ pln_b,
    const float* __restrict__ Wb, const float* __restrict__ bb,
    const float* __restrict__ qkv, float* __restrict__ ex_out,
    float* __restrict__ denom) {
  __shared__ __align__(16) float pn_s[4][PAIR];
  int w = threadIdx.x >> 6;
  int lane = threadIdx.x & 63;
  int e = blockIdx.x * 4 + w;           // N_EDGE % 4 == 0: no guard needed
  int src = edge_index[e * 2 + 0];
  int dst = edge_index[e * 2 + 1];

  // ---- pair LayerNorm (128 elems, 2 per lane) ----
  float2 p = *(const float2*)(pair + (size_t)e * PAIR + lane * 2);
  float s = p.x + p.y, s2 = p.x * p.x + p.y * p.y;
  #pragma unroll
  for (int off = 32; off > 0; off >>= 1) {
    s  += __shfl_xor(s,  off);
    s2 += __shfl_xor(s2, off);
  }
  float m = s * (1.0f / PAIR);
  float rstd = rsqrtf(s2 * (1.0f / PAIR) - m * m + LNEPS);
  float2 plw = *(const float2*)(pln_w + lane * 2);
  float2 plb = *(const float2*)(pln_b + lane * 2);
  pn_s[w][lane * 2 + 0] = (p.x - m) * rstd * plw.x + plb.x;
  pn_s[w][lane * 2 + 1] = (p.y - m) * rstd * plw.y + plb.y;
  __syncthreads();

  // ---- per-head logit: lane = h*4 + p ----
  int h = lane >> 2, pq = lane & 3;
  float4 qv = *(const float4*)(qkv + (size_t)src * 768 + lane * 4);
  float4 kv = *(const float4*)(qkv + (size_t)dst * 768 + 256 + lane * 4);
  float lp = SCALING * (qv.x * kv.x + qv.y * kv.y + qv.z * kv.z + qv.w * kv.w);

  const float4* wbrow = (const float4*)(Wb + h * PAIR + pq * 32);
  const float4* pnrow = (const float4*)(&pn_s[w][pq * 32]);
  #pragma unroll
  for (int i = 0; i < 8; i++) {
    float4 wb = wbrow[i];
    float4 pn = pnrow[i];
    lp += wb.x * pn.x + wb.y * pn.y + wb.z * pn.z + wb.w * pn.w;
  }
  lp += __shfl_xor(lp, 1);
  lp += __shfl_xor(lp, 2);
  if (pq == 0) {
    // logits are O(1) by construction: exp without max-shift is safe and
    // cancels identically in probs = ex/denom.
    float exv = expf(lp + bb[h]);
    ex_out[(size_t)e * HEADS + h] = exv;
    atomicAdd(&denom[src * HEADS + h], exv);
  }
}

// ------------------------------------------------------------------
// Kernel 6: per-edge accumulate into out. One thread per edge.
__global__ __launch_bounds__(256) void edge_accum_kernel(
    const int* __restrict__ edge_index, const float* __restrict__ edge_diff,
    const float* __restrict__ ex, const float* __restrict__ denom,
    const float* __restrict__ vw, float* __restrict__ out) {
  int e = blockIdx.x * blockDim.x + threadIdx.x;
  if (e >= N_EDGE) return;
  int src = edge_index[e * 2 + 0];
  int dst = edge_index[e * 2 + 1];
  const float* exe = ex + (size_t)e * HEADS;
  const float* dn = denom + src * HEADS;
  const float* vwd = vw + dst * 48;
  float v0 = 0.f, v1 = 0.f, v2 = 0.f;
  #pragma unroll
  for (int hh = 0; hh < HEADS; hh++) {
    float pr = exe[hh] / dn[hh];
    v0 += pr * vwd[hh * 3 + 0];
    v1 += pr * vwd[hh * 3 + 1];
    v2 += pr * vwd[hh * 3 + 2];
  }
  atomicAdd(&out[src * 3 + 0], edge_diff[e * 3 + 0] * v0);
  atomicAdd(&out[src * 3 + 1], edge_diff[e * 3 + 1] * v1);
  atomicAdd(&out[src * 3 + 2], edge_diff[e * 3 + 2] * v2);
}

// ------------------------------------------------------------------
extern "C" void kernel_launch(void* const* d_in, const int* in_sizes, int n_in,
                              void* d_out, int out_size, void* d_ws,
                              size_t ws_size, hipStream_t stream) {
  const float* query      = (const float*)d_in[0];
  const int*   edge_index = (const int*)d_in[1];
  const float* edge_diff  = (const float*)d_in[2];
  const float* pair       = (const float*)d_in[3];
  const float* ln_w       = (const float*)d_in[4];
  const float* ln_b       = (const float*)d_in[5];
  const float* pln_w      = (const float*)d_in[6];
  const float* pln_b      = (const float*)d_in[7];
  const float* Wq         = (const float*)d_in[8];
  const float* Wk         = (const float*)d_in[9];
  const float* Wv         = (const float*)d_in[10];
  const float* Wb         = (const float*)d_in[11];
  const float* bb         = (const float*)d_in[12];
  const float* Wf1        = (const float*)d_in[13];
  const float* bf1        = (const float*)d_in[14];
  const float* Wf2        = (const float*)d_in[15];
  const float* bf2        = (const float*)d_in[16];
  const float* Wf3        = (const float*)d_in[17];
  const float* bf3        = (const float*)d_in[18];

  char* ws = (char*)d_ws;
  float* qkv   = (float*)(ws + WS_QKV);
  float* exb   = (float*)(ws + WS_EX);
  float* denom = (float*)(ws + WS_DENOM);
  float* vw    = (float*)(ws + WS_VW);
  float* mean_ = (float*)(ws + WS_MEAN);
  float* rstd_ = (float*)(ws + WS_RSTD);
  float* out   = (float*)d_out;

  // 1. LN stats: 20000 nodes, 4 per block
  ln_stats_kernel<<<N_NODE / 4, 256, 0, stream>>>(query, mean_, rstd_);

  // 2. fused-LN GEMM -> qkv
  dim3 ggrid((N_NODE + BM - 1) / BM, 768 / BN);
  qkv_gemm_kernel<<<ggrid, 256, 0, stream>>>(query, mean_, rstd_, ln_w, ln_b,
                                             Wq, Wk, Wv, qkv);

  // 3. vw precompute
  vw_kernel<<<(N_NODE * 48) / 256, 256, 0, stream>>>(qkv, Wf1, Wf2, Wf3, vw);

  // 4. init denom + out
  init_kernel<<<(N_NODE * HEADS) / 256, 256, 0, stream>>>(denom, out, bf1, bf2,
                                                          bf3);

  // 5. edge logits -> ex, denom
  edge_logits_kernel<<<N_EDGE / 4, 256, 0, stream>>>(
      edge_index, pair, pln_w, pln_b, Wb, bb, qkv, exb, denom);

  // 6. edge accumulate -> out
  edge_accum_kernel<<<(N_EDGE + 255) / 256, 256, 0, stream>>>(
      edge_index, edge_diff, exb, denom, vw, out);
}

// Round 2
// 308.261 us; speedup vs baseline: 1.7862x; 1.7862x over previous
//
#include <hip/hip_runtime.h>
#include <math.h>

#define N_NODE 20000
#define N_EDGE 200000
#define EMBED 256
#define PAIR 128
#define HEADS 16
#define HEAD_DIM 16
#define SCALING 0.25f
#define LNEPS 1e-5f

typedef unsigned short u16;
typedef unsigned int u32;
typedef __attribute__((ext_vector_type(8))) short bf16x8;
typedef __attribute__((ext_vector_type(4))) float f32x4;

// ---------------- workspace layout (bytes) ----------------
#define WS_QKV   0            // qkv_bf : 20000*768*2  = 30,720,000 (q scaled)
#define WS_EX    30720000     // ex     : 200000*16*4  = 12,800,000
#define WS_DENOM 43520000     // denom  : 320000*4     =  1,280,000
#define WS_VW    44800000     // vw     : 20000*48*4   =  3,840,000
#define WS_QN    48640000     // qn_bf  : 20000*256*2  = 10,240,000
#define WS_WBF   58880000     // Wbf    : 768*256*2    =    393,216
#define WS_WW    59273216     // WW_bf  : 16*128*2     =      4,096
#define WS_C0    59277312     // c0     : 16*4 (pad 64)
#define WS_C1    59277376     // c1     : 16*4 (pad 64)
#define WS_BIAS  59277440     // bias   : 200000*16*4  = 12,800,000

__device__ __forceinline__ u16 f2bf(float f) {
  u32 u = __float_as_uint(f);
  u32 r = (u + 0x7FFFu + ((u >> 16) & 1u)) >> 16;
  return (u16)r;
}
__device__ __forceinline__ float bl(u32 u) { return __uint_as_float(u << 16); }
__device__ __forceinline__ float bh(u32 u) { return __uint_as_float(u & 0xFFFF0000u); }

__device__ __forceinline__ float dot8(uint4 a, uint4 b) {
  float s = bl(a.x) * bl(b.x) + bh(a.x) * bh(b.x);
  s += bl(a.y) * bl(b.y) + bh(a.y) * bh(b.y);
  s += bl(a.z) * bl(b.z) + bh(a.z) * bh(b.z);
  s += bl(a.w) * bl(b.w) + bh(a.w) * bh(b.w);
  return s;
}

// ------------------------------------------------------------------
// K1: per-node LN -> qn_bf (bf16). One wave per node, 4 per block.
__global__ __launch_bounds__(256) void ln_qn_kernel(
    const float* __restrict__ query, const float* __restrict__ ln_w,
    const float* __restrict__ ln_b, u16* __restrict__ qn) {
  int node = blockIdx.x * 4 + (threadIdx.x >> 6);
  int lane = threadIdx.x & 63;
  float4 a = *(const float4*)(query + (size_t)node * EMBED + lane * 4);
  float s = a.x + a.y + a.z + a.w;
  float s2 = a.x * a.x + a.y * a.y + a.z * a.z + a.w * a.w;
  #pragma unroll
  for (int off = 32; off > 0; off >>= 1) {
    s += __shfl_xor(s, off);
    s2 += __shfl_xor(s2, off);
  }
  float m = s * (1.0f / EMBED);
  float r = rsqrtf(s2 * (1.0f / EMBED) - m * m + LNEPS);
  float4 w4 = *(const float4*)(ln_w + lane * 4);
  float4 b4 = *(const float4*)(ln_b + lane * 4);
  ushort4 st;
  st.x = f2bf((a.x - m) * r * w4.x + b4.x);
  st.y = f2bf((a.y - m) * r * w4.y + b4.y);
  st.z = f2bf((a.z - m) * r * w4.z + b4.z);
  st.w = f2bf((a.w - m) * r * w4.w + b4.w);
  *(ushort4*)(qn + (size_t)node * EMBED + lane * 4) = st;
}

// ------------------------------------------------------------------
// K2: Wq|Wk|Wv -> Wbf (768x256 bf16), row j = output feature j.
__global__ __launch_bounds__(256) void wcvt_kernel(
    const float* __restrict__ Wq, const float* __restrict__ Wk,
    const float* __restrict__ Wv, u16* __restrict__ Wbf) {
  int g4 = blockIdx.x * 256 + threadIdx.x;  // 49152 float4 groups
  int idx = g4 * 4;
  const float* src = (idx < 65536) ? Wq : (idx < 131072 ? Wk : Wv);
  float4 v = *(const float4*)(src + (idx & 65535));
  ushort4 st = {f2bf(v.x), f2bf(v.y), f2bf(v.z), f2bf(v.w)};
  *(ushort4*)(Wbf + idx) = st;
}

// ------------------------------------------------------------------
// K3: WW_bf[h][i] = bf16(plw[i]*Wb[h][i]); c1[h]=sum WW; c0[h]=sum plb*Wb + bb.
__global__ __launch_bounds__(64) void prep_kernel(
    const float* __restrict__ pln_w, const float* __restrict__ pln_b,
    const float* __restrict__ Wb, const float* __restrict__ bb,
    u16* __restrict__ WWbf, float* __restrict__ c0, float* __restrict__ c1) {
  int h = blockIdx.x, l = threadIdx.x;
  int i0 = l * 2;
  float wb0 = Wb[h * PAIR + i0], wb1 = Wb[h * PAIR + i0 + 1];
  float ww0 = pln_w[i0] * wb0, ww1 = pln_w[i0 + 1] * wb1;
  WWbf[h * PAIR + i0] = f2bf(ww0);
  WWbf[h * PAIR + i0 + 1] = f2bf(ww1);
  float s1 = ww0 + ww1;
  float s0 = pln_b[i0] * wb0 + pln_b[i0 + 1] * wb1;
  #pragma unroll
  for (int off = 32; off > 0; off >>= 1) {
    s1 += __shfl_xor(s1, off);
    s0 += __shfl_xor(s0, off);
  }
  if (l == 0) {
    c1[h] = s1;
    c0[h] = s0 + bb[h];
  }
}

// ------------------------------------------------------------------
// K4: init denom=0, out = final biases.
__global__ __launch_bounds__(256) void init_kernel(
    float* __restrict__ denom, float* __restrict__ out,
    const float* __restrict__ bf1, const float* __restrict__ bf2,
    const float* __restrict__ bf3) {
  int i = blockIdx.x * 256 + threadIdx.x;
  if (i < N_NODE * HEADS) denom[i] = 0.0f;
  if (i < N_NODE) {
    out[i * 3 + 0] = bf1[0];
    out[i * 3 + 1] = bf2[0];
    out[i * 3 + 2] = bf3[0];
  }
}

// ------------------------------------------------------------------
// K5: bf16 MFMA GEMM: qkv[n][j] = qn[n] . Wbf[j], j in 0..767.
// 64x64 tile, full K=256 staged once. LDS rows padded to 264 ushorts (528 B).
#define GP 264
__global__ __launch_bounds__(256, 2) void qkv_gemm_kernel(
    const u16* __restrict__ qn, const u16* __restrict__ Wbf,
    u16* __restrict__ qkv) {
  __shared__ u16 As[64 * GP];
  __shared__ u16 Bs[64 * GP];
  int t = threadIdx.x;
  int wv = t >> 6, lane = t & 63;
  int quad = lane >> 4, l16 = lane & 15;
  int row0 = blockIdx.x * 64, col0 = blockIdx.y * 64;
  #pragma unroll
  for (int j = 0; j < 8; j++) {
    int row = j * 8 + (t >> 5);
    int slot = t & 31;
    int ra = min(row0 + row, N_NODE - 1);
    uint4 va = *(const uint4*)(qn + (size_t)ra * 256 + slot * 8);
    *(uint4*)(&As[row * GP + slot * 8]) = va;
    uint4 vb = *(const uint4*)(Wbf + (size_t)(col0 + row) * 256 + slot * 8);
    *(uint4*)(&Bs[row * GP + slot * 8]) = vb;
  }
  __syncthreads();
  int mt = (wv >> 1) * 32, nt = (wv & 1) * 32;
  f32x4 acc[2][2];
  #pragma unroll
  for (int im = 0; im < 2; im++)
    #pragma unroll
    for (int in_ = 0; in_ < 2; in_++) acc[im][in_] = (f32x4){0.f, 0.f, 0.f, 0.f};
  #pragma unroll
  for (int sk = 0; sk < 8; sk++) {
    int ko = sk * 32 + quad * 8;
    bf16x8 a0 = *(const bf16x8*)(&As[(mt + l16) * GP + ko]);
    bf16x8 a1 = *(const bf16x8*)(&As[(mt + 16 + l16) * GP + ko]);
    bf16x8 b0 = *(const bf16x8*)(&Bs[(nt + l16) * GP + ko]);
    bf16x8 b1 = *(const bf16x8*)(&Bs[(nt + 16 + l16) * GP + ko]);
    acc[0][0] = __builtin_amdgcn_mfma_f32_16x16x32_bf16(a0, b0, acc[0][0], 0, 0, 0);
    acc[0][1] = __builtin_amdgcn_mfma_f32_16x16x32_bf16(a0, b1, acc[0][1], 0, 0, 0);
    acc[1][0] = __builtin_amdgcn_mfma_f32_16x16x32_bf16(a1, b0, acc[1][0], 0, 0, 0);
    acc[1][1] = __builtin_amdgcn_mfma_f32_16x16x32_bf16(a1, b1, acc[1][1], 0, 0, 0);
  }
  float scale = (col0 < 256) ? SCALING : 1.0f;
  #pragma unroll
  for (int im = 0; im < 2; im++) {
    #pragma unroll
    for (int in_ = 0; in_ < 2; in_++) {
      #pragma unroll
      for (int r = 0; r < 4; r++) {
        int grow = row0 + mt + im * 16 + quad * 4 + r;
        int gcol = col0 + nt + in_ * 16 + l16;
        if (grow < N_NODE)
          qkv[(size_t)grow * 768 + gcol] = f2bf(acc[im][in_][r] * scale);
      }
    }
  }
}

// ------------------------------------------------------------------
// K6: vw[n][h][c] = sum_d v[n,h*16+d]*Wf_c[h*16+d], v from qkv bf16.
__global__ __launch_bounds__(256) void vw_kernel(
    const u16* __restrict__ qkv, const float* __restrict__ Wf1,
    const float* __restrict__ Wf2, const float* __restrict__ Wf3,
    float* __restrict__ vw) {
  int gid = blockIdx.x * 256 + threadIdx.x;  // 320000
  int n = gid >> 4, h = gid & 15;
  const uint4* vp = (const uint4*)(qkv + (size_t)n * 768 + 512 + h * 16);
  uint4 va = vp[0], vb = vp[1];
  float v[16];
  v[0] = bl(va.x); v[1] = bh(va.x); v[2] = bl(va.y); v[3] = bh(va.y);
  v[4] = bl(va.z); v[5] = bh(va.z); v[6] = bl(va.w); v[7] = bh(va.w);
  v[8] = bl(vb.x); v[9] = bh(vb.x); v[10] = bl(vb.y); v[11] = bh(vb.y);
  v[12] = bl(vb.z); v[13] = bh(vb.z); v[14] = bl(vb.w); v[15] = bh(vb.w);
  const float* wf[3] = {Wf1 + h * 16, Wf2 + h * 16, Wf3 + h * 16};
  #pragma unroll
  for (int c = 0; c < 3; c++) {
    float s = 0.f;
    #pragma unroll
    for (int d = 0; d < 16; d++) s += v[d] * wf[c][d];
    vw[(size_t)n * 48 + h * 3 + c] = s;
  }
}

// ------------------------------------------------------------------
// K7: pair bias via MFMA: bias[e][h] = r_e*(p_e.WW_h - m_e*c1_h) + c0_h.
// Block: 64 edges. LDS: Ps 64x136 u16, WWs 16x136 u16.
#define PP 136
__global__ __launch_bounds__(256) void pair_bias_kernel(
    const float* __restrict__ pair, const u16* __restrict__ WWbf,
    const float* __restrict__ c0g, const float* __restrict__ c1g,
    float* __restrict__ bias) {
  __shared__ u16 Ps[64 * PP];
  __shared__ u16 WWs[16 * PP];
  __shared__ float ms[64], rs[64], c0s[16], c1s[16];
  int t = threadIdx.x;
  int wv = t >> 6, lane = t & 63;
  int quad = lane >> 4, l16 = lane & 15;
  int e0 = blockIdx.x * 64;
  // stage pair (fp32 -> bf16) coalesced
  #pragma unroll
  for (int j = 0; j < 8; j++) {
    int L = j * 256 + t;
    int row = L >> 5, slot = L & 31;
    float4 p = *(const float4*)(pair + (size_t)(e0 + row) * PAIR + slot * 4);
    ushort4 st = {f2bf(p.x), f2bf(p.y), f2bf(p.z), f2bf(p.w)};
    *(ushort4*)(&Ps[row * PP + slot * 4]) = st;
  }
  // stage WW
  #pragma unroll
  for (int j = 0; j < 2; j++) {
    int L = j * 256 + t;
    int row = L >> 5, slot = L & 31;
    ushort4 w = *(const ushort4*)(WWbf + row * PAIR + slot * 4);
    *(ushort4*)(&WWs[row * PP + slot * 4]) = w;
  }
  if (t < 16) {
    c0s[t] = c0g[t];
    c1s[t] = c1g[t];
  }
  __syncthreads();
  // per-edge stats from staged bf16
  {
    int row = t >> 2, qq = t & 3;
    float s = 0.f, s2 = 0.f;
    #pragma unroll
    for (int jj = 0; jj < 8; jj++) {
      ushort4 u = *(const ushort4*)(&Ps[row * PP + (qq * 8 + jj) * 4]);
      float x0 = __uint_as_float((u32)u.x << 16);
      float x1 = __uint_as_float((u32)u.y << 16);
      float x2 = __uint_as_float((u32)u.z << 16);
      float x3 = __uint_as_float((u32)u.w << 16);
      s += x0 + x1 + x2 + x3;
      s2 += x0 * x0 + x1 * x1 + x2 * x2 + x3 * x3;
    }
    s += __shfl_xor(s, 1); s += __shfl_xor(s, 2);
    s2 += __shfl_xor(s2, 1); s2 += __shfl_xor(s2, 2);
    if (qq == 0) {
      float m = s * (1.0f / PAIR);
      ms[row] = m;
      rs[row] = rsqrtf(s2 * (1.0f / PAIR) - m * m + LNEPS);
    }
  }
  __syncthreads();
  // MFMA: A = Ps (edges x 128), B^T = WWs (heads x 128)
  f32x4 acc = (f32x4){0.f, 0.f, 0.f, 0.f};
  #pragma unroll
  for (int sk = 0; sk < 4; sk++) {
    int ko = sk * 32 + quad * 8;
    bf16x8 a = *(const bf16x8*)(&Ps[(wv * 16 + l16) * PP + ko]);
    bf16x8 b = *(const bf16x8*)(&WWs[l16 * PP + ko]);
    acc = __builtin_amdgcn_mfma_f32_16x16x32_bf16(a, b, acc, 0, 0, 0);
  }
  #pragma unroll
  for (int r = 0; r < 4; r++) {
    int el = wv * 16 + quad * 4 + r;
    float bv = rs[el] * (acc[r] - ms[el] * c1s[l16]) + c0s[l16];
    bias[(size_t)(e0 + el) * HEADS + l16] = bv;
  }
}

// ------------------------------------------------------------------
// K8: thread per (edge, head): ex = exp(q.k + bias); denom += ex.
__global__ __launch_bounds__(256) void qk_exp_kernel(
    const int* __restrict__ edge_index, const u16* __restrict__ qkv,
    const float* __restrict__ bias, float* __restrict__ ex,
    float* __restrict__ denom) {
  int gid = blockIdx.x * 256 + threadIdx.x;  // 3.2M
  int e = gid >> 4, h = gid & 15;
  int src = edge_index[e * 2 + 0];
  int dst = edge_index[e * 2 + 1];
  const uint4* qp = (const uint4*)(qkv + (size_t)src * 768 + h * 16);
  const uint4* kp = (const uint4*)(qkv + (size_t)dst * 768 + 256 + h * 16);
  uint4 q0 = qp[0], q1 = qp[1];
  uint4 k0 = kp[0], k1 = kp[1];
  float d = dot8(q0, k0) + dot8(q1, k1);  // SCALING folded into q
  float exv = __expf(d + bias[gid]);
  ex[gid] = exv;
  atomicAdd(&denom[src * HEADS + h], exv);
}

// ------------------------------------------------------------------
// K9: denom -> 1/denom in place.
__global__ __launch_bounds__(256) void recip_kernel(float* __restrict__ denom) {
  int i = blockIdx.x * 256 + threadIdx.x;
  if (i < N_NODE * HEADS) denom[i] = 1.0f / denom[i];
}

// ------------------------------------------------------------------
// K10: thread per (edge, head), shuffle-reduce over 16 heads, atomics by h==0.
__global__ __launch_bounds__(256) void edge_accum_kernel(
    const int* __restrict__ edge_index, const float* __restrict__ edge_diff,
    const float* __restrict__ ex, const float* __restrict__ rdenom,
    const float* __restrict__ vw, float* __restrict__ out) {
  int gid = blockIdx.x * 256 + threadIdx.x;
  int e = gid >> 4, h = gid & 15;
  int src = edge_index[e * 2 + 0];
  int dst = edge_index[e * 2 + 1];
  float pr = ex[gid] * rdenom[src * HEADS + h];
  const float* vwd = vw + (size_t)dst * 48 + h * 3;
  float v0 = pr * vwd[0], v1 = pr * vwd[1], v2 = pr * vwd[2];
  #pragma unroll
  for (int off = 8; off > 0; off >>= 1) {
    v0 += __shfl_xor(v0, off);
    v1 += __shfl_xor(v1, off);
    v2 += __shfl_xor(v2, off);
  }
  if (h == 0) {
    atomicAdd(&out[src * 3 + 0], edge_diff[e * 3 + 0] * v0);
    atomicAdd(&out[src * 3 + 1], edge_diff[e * 3 + 1] * v1);
    atomicAdd(&out[src * 3 + 2], edge_diff[e * 3 + 2] * v2);
  }
}

// ------------------------------------------------------------------
extern "C" void kernel_launch(void* const* d_in, const int* in_sizes, int n_in,
                              void* d_out, int out_size, void* d_ws,
                              size_t ws_size, hipStream_t stream) {
  const float* query      = (const float*)d_in[0];
  const int*   edge_index = (const int*)d_in[1];
  const float* edge_diff  = (const float*)d_in[2];
  const float* pair       = (const float*)d_in[3];
  const float* ln_w       = (const float*)d_in[4];
  const float* ln_b       = (const float*)d_in[5];
  const float* pln_w      = (const float*)d_in[6];
  const float* pln_b      = (const float*)d_in[7];
  const float* Wq         = (const float*)d_in[8];
  const float* Wk         = (const float*)d_in[9];
  const float* Wv         = (const float*)d_in[10];
  const float* Wb         = (const float*)d_in[11];
  const float* bb         = (const float*)d_in[12];
  const float* Wf1        = (const float*)d_in[13];
  const float* bf1        = (const float*)d_in[14];
  const float* Wf2        = (const float*)d_in[15];
  const float* bf2        = (const float*)d_in[16];
  const float* Wf3        = (const float*)d_in[17];
  const float* bf3        = (const float*)d_in[18];

  char* ws = (char*)d_ws;
  u16*   qkv   = (u16*)(ws + WS_QKV);
  float* exb   = (float*)(ws + WS_EX);
  float* denom = (float*)(ws + WS_DENOM);
  float* vw    = (float*)(ws + WS_VW);
  u16*   qn    = (u16*)(ws + WS_QN);
  u16*   Wbf   = (u16*)(ws + WS_WBF);
  u16*   WWbf  = (u16*)(ws + WS_WW);
  float* c0    = (float*)(ws + WS_C0);
  float* c1    = (float*)(ws + WS_C1);
  float* bias  = (float*)(ws + WS_BIAS);
  float* out   = (float*)d_out;

  ln_qn_kernel<<<N_NODE / 4, 256, 0, stream>>>(query, ln_w, ln_b, qn);
  wcvt_kernel<<<192, 256, 0, stream>>>(Wq, Wk, Wv, Wbf);
  prep_kernel<<<16, 64, 0, stream>>>(pln_w, pln_b, Wb, bb, WWbf, c0, c1);
  init_kernel<<<1250, 256, 0, stream>>>(denom, out, bf1, bf2, bf3);
  dim3 ggrid((N_NODE + 63) / 64, 12);
  qkv_gemm_kernel<<<ggrid, 256, 0, stream>>>(qn, Wbf, qkv);
  vw_kernel<<<1250, 256, 0, stream>>>(qkv, Wf1, Wf2, Wf3, vw);
  pair_bias_kernel<<<N_EDGE / 64, 256, 0, stream>>>(pair, WWbf, c0, c1, bias);
  qk_exp_kernel<<<N_EDGE * HEADS / 256, 256, 0, stream>>>(edge_index, qkv, bias,
                                                          exb, denom);
  recip_kernel<<<1250, 256, 0, stream>>>(denom);
  edge_accum_kernel<<<N_EDGE * HEADS / 256, 256, 0, stream>>>(
      edge_index, edge_diff, exb, denom, vw, out);
}